// Round 1
// baseline (341.566 us; speedup 1.0000x reference)
//
#include <hip/hip_runtime.h>
#include <math.h>

#define TT 2000

// Fused single-block kernel:
//  Phase 1 (256 threads): stream obs (2000x128 f32) once; compute per-row
//    group sums s[g][t] (into LDS), column sums, sum of squares per group,
//    sum of s^2 per group.
//  Phase 2 (lanes 0,1 of wave 0): two independent 3-state Kalman filters
//    (pos, vel, mean-bias) with scalar observations z = s/8, h = (8,0,1).
//  Static bias modes (126 of them) contribute in closed form.
__global__ __launch_bounds__(256) void kf_fused(
    const float* __restrict__ obs,
    const float* __restrict__ p_lbs,   // log_bias_scale
    const float* __restrict__ p_lon,   // log_obs_noise
    const float* __restrict__ p_ltn,   // log_trans_noise
    float* __restrict__ out)           // 21 floats: logp, mean(4), cov(16)
{
    __shared__ float s_lds[2][2048];   // per-group row sums
    __shared__ float Ycols[128];       // column sums
    __shared__ float sh_sq[2];         // sum y^2 per group
    __shared__ float sh_ssq[2];        // sum s^2 per group
    __shared__ float sh_stats[2][2];   // per group: {sum Ycols, sum Ycols^2}

    const int tid = threadIdx.x;
    if (tid < 128) Ycols[tid] = 0.0f;
    if (tid < 2) { sh_sq[tid] = 0.0f; sh_ssq[tid] = 0.0f; }
    __syncthreads();

    // ---- Phase 1: data reductions ----
    // thread -> (row offset rho = tid>>5 in 0..7, quad q = tid&31 -> cols 4q..4q+3)
    const int q   = tid & 31;
    const int rho = tid >> 5;
    const int g   = q >> 4;   // cols 0..63 -> group 0, 64..127 -> group 1

    float c0=0.f, c1=0.f, c2=0.f, c3=0.f, sq=0.f, ssq_acc=0.f;
    const float4* obs4 = reinterpret_cast<const float4*>(obs);
    for (int i = 0; i < TT/8; ++i) {
        const int row = i*8 + rho;
        const float4 v = obs4[row*32 + q];
        c0 += v.x; c1 += v.y; c2 += v.z; c3 += v.w;
        sq += v.x*v.x + v.y*v.y + v.z*v.z + v.w*v.w;
        float s = (v.x + v.y) + (v.z + v.w);
        // reduce across the 16 lanes covering this (row, group)
        s += __shfl_xor(s, 1);
        s += __shfl_xor(s, 2);
        s += __shfl_xor(s, 4);
        s += __shfl_xor(s, 8);
        if ((q & 15) == 0) {
            s_lds[g][row] = s;
            ssq_acc += s*s;
        }
    }
    atomicAdd(&sh_sq[g], sq);
    if ((q & 15) == 0) atomicAdd(&sh_ssq[g], ssq_acc);
    atomicAdd(&Ycols[4*q+0], c0);
    atomicAdd(&Ycols[4*q+1], c1);
    atomicAdd(&Ycols[4*q+2], c2);
    atomicAdd(&Ycols[4*q+3], c3);
    __syncthreads();

    // per-group stats of column sums: wave0 -> group0 cols, wave1 -> group1
    if (tid < 128) {
        const int w = tid >> 6;
        const int lane = tid & 63;
        const float y = Ycols[w*64 + lane];
        float su = y, s2 = y*y;
        #pragma unroll
        for (int m = 1; m < 64; m <<= 1) {
            su += __shfl_xor(su, m);
            s2 += __shfl_xor(s2, m);
        }
        if (lane == 0) { sh_stats[w][0] = su; sh_stats[w][1] = s2; }
    }
    __syncthreads();
    if (tid >= 64) return;

    // ---- Phase 2: two 3-state Kalman filters (SIMT in lanes 0,1) ----
    const float sb2 = expf(2.0f * p_lbs[0]);   // bias_var
    const float so2 = expf(2.0f * p_lon[0]);   // obs_var
    const float tv  = expf(2.0f * p_ltn[0]);   // trans_var
    const float LOG2PI_F = 1.8378770664093453f;

    float p = 0.f, vv = 0.f, B = 0.f;
    float Ppp = 10000.f, Ppv = 0.f, PpB = 0.f, Pvv = 10000.f, PvB = 0.f, PBB = sb2;
    double ll = 0.0;

    if (tid < 2) {
        const float tv3  = tv * (1.0f/3.0f);
        const float tv2h = tv * 0.5f;
        const float* zrow = s_lds[tid];
        for (int t = 0; t < TT; ++t) {
            // predict: x = Fx, P = F P F^T + Q  (F = [[1,1],[0,1]] on (p,v))
            p += vv;
            Ppp += 2.0f*Ppv + Pvv + tv3;
            Ppv += Pvv + tv2h;
            PpB += PvB;
            Pvv += tv;
            // scalar measurement update: z = s/8, h = (8,0,1), R = so2
            const float z   = zrow[t] * 0.125f;
            const float Php = 8.0f*Ppp + PpB;
            const float Phv = 8.0f*Ppv + PvB;
            const float PhB = 8.0f*PpB + PBB;
            const float S   = 8.0f*Php + PhB + so2;
            const float r   = z - (8.0f*p + B);
            const float inv = 1.0f / S;
            ll -= 0.5 * (double)(r*r*inv + __logf(S) + LOG2PI_F);
            const float kp = Php*inv, kv = Phv*inv, kB = PhB*inv;
            p  += kp*r;  vv += kv*r;  B  += kB*r;
            Ppp -= kp*Php; Ppv -= kp*Phv; PpB -= kp*PhB;
            Pvv -= kv*Phv; PvB -= kv*PhB; PBB -= kB*PhB;
        }
    }

    // pull lane 1's results to lane 0 (all lanes 0..63 active here)
    const float  p1   = __shfl(p, 1);
    const float  v1   = __shfl(vv, 1);
    const float  Ppp1 = __shfl(Ppp, 1);
    const float  Ppv1 = __shfl(Ppv, 1);
    const float  Pvv1 = __shfl(Pvv, 1);
    const double ll1  = __shfl(ll, 1);

    if (tid == 0) {
        // static-mode (bias-only) closed-form evidence:
        // per group, 63 modes z ~ N(0, so2 I_T + sb2 11^T)
        const float Q0 = sh_sq[0] - sh_ssq[0]*(1.0f/64.0f);
        const float Q1 = sh_sq[1] - sh_ssq[1]*(1.0f/64.0f);
        const float R0 = sh_stats[0][1] - sh_stats[0][0]*sh_stats[0][0]*(1.0f/64.0f);
        const float R1 = sh_stats[1][1] - sh_stats[1][0]*sh_stats[1][0]*(1.0f/64.0f);
        const double DLOG2PI = 1.8378770664093453;
        const double Td = (double)TT;
        const double denom = (double)so2 + Td*(double)sb2;
        double ll_static = -0.5*((double)Q0 + (double)Q1
                                 - (double)sb2*((double)R0 + (double)R1)/denom) / (double)so2;
        ll_static += -0.5*126.0*((Td - 1.0)*log((double)so2) + log(denom));
        ll_static += -0.5*126.0*Td*DLOG2PI;

        const double total = ll + ll1 + ll_static;
        out[0] = (float)total;
        // post_mean: filter0 = (x0, x2), filter1 = (x1, x3)
        out[1] = p;  out[2] = p1; out[3] = vv; out[4] = v1;
        // post_cov 4x4 row-major; cross terms between the two filters are exactly 0
        float C[16];
        #pragma unroll
        for (int i = 0; i < 16; ++i) C[i] = 0.0f;
        C[0]  = Ppp;  C[2]  = Ppv;  C[8]  = Ppv;  C[10] = Pvv;
        C[5]  = Ppp1; C[7]  = Ppv1; C[13] = Ppv1; C[15] = Pvv1;
        #pragma unroll
        for (int i = 0; i < 16; ++i) out[5+i] = C[i];
    }
}

extern "C" void kernel_launch(void* const* d_in, const int* in_sizes, int n_in,
                              void* d_out, int out_size, void* d_ws, size_t ws_size,
                              hipStream_t stream) {
    const float* obs = (const float*)d_in[0];
    const float* lbs = (const float*)d_in[1];
    const float* lon = (const float*)d_in[2];
    const float* ltn = (const float*)d_in[3];
    float* out = (float*)d_out;
    hipLaunchKernelGGL(kf_fused, dim3(1), dim3(256), 0, stream,
                       obs, lbs, lon, ltn, out);
}

// Round 2
// 67.403 us; speedup vs baseline: 5.0675x; 5.0675x over previous
//
#include <hip/hip_runtime.h>
#include <math.h>

#define TT 2000
#define T0 336                 // exact sequential steps (multiple of 8)
#define NREM (TT - T0)         // 1664 = 128 * 13
#define CH 13                  // chunk length per thread (per group)
#define NBLK_A 50
#define ROWS_PER_BLK 40        // 50*40 = 2000
#define WS_PART 4096           // float offset of per-block partials
#define PART_STRIDE 132        // 128 cols + 2 sq + pad
#define WS_FLOATS (WS_PART + NBLK_A * PART_STRIDE)

__device__ __forceinline__ void mmul3(const float* __restrict__ a,
                                      const float* __restrict__ b,
                                      float* __restrict__ c) {
#pragma unroll
    for (int r = 0; r < 3; ++r)
#pragma unroll
        for (int cc = 0; cc < 3; ++cc)
            c[3*r+cc] = a[3*r+0]*b[0+cc] + a[3*r+1]*b[3+cc] + a[3*r+2]*b[6+cc];
}

// ---------------- Kernel A: grid-parallel data reductions ----------------
// Writes: ws[g*2048 + t] = group row sum s[g][t]
//         ws[WS_PART + b*PART_STRIDE + c]   (c<128): partial column sums
//         ws[WS_PART + b*PART_STRIDE + 128 + g]: partial sum of y^2 per group
__global__ __launch_bounds__(256) void kA(const float* __restrict__ obs,
                                          float* __restrict__ ws) {
    __shared__ float cols_l[128];
    __shared__ float sq_l[2];
    const int tid = threadIdx.x, b = blockIdx.x;
    if (tid < 128) cols_l[tid] = 0.0f;
    if (tid < 2)   sq_l[tid]   = 0.0f;
    __syncthreads();

    const int q = tid & 31, rho = tid >> 5, g = q >> 4;
    float c0=0.f, c1=0.f, c2=0.f, c3=0.f, sq=0.f;
    const float4* obs4 = reinterpret_cast<const float4*>(obs);
    for (int i = 0; i < ROWS_PER_BLK/8; ++i) {
        const int row = b*ROWS_PER_BLK + i*8 + rho;
        const float4 v = obs4[row*32 + q];
        c0 += v.x; c1 += v.y; c2 += v.z; c3 += v.w;
        sq += v.x*v.x + v.y*v.y + v.z*v.z + v.w*v.w;
        float s = (v.x + v.y) + (v.z + v.w);
        s += __shfl_xor(s, 1);
        s += __shfl_xor(s, 2);
        s += __shfl_xor(s, 4);
        s += __shfl_xor(s, 8);
        if ((q & 15) == 0) ws[g*2048 + row] = s;
    }
    atomicAdd(&cols_l[4*q+0], c0);
    atomicAdd(&cols_l[4*q+1], c1);
    atomicAdd(&cols_l[4*q+2], c2);
    atomicAdd(&cols_l[4*q+3], c3);
    atomicAdd(&sq_l[g], sq);
    __syncthreads();

    float* part = ws + WS_PART + b*PART_STRIDE;
    if (tid < 128) part[tid] = cols_l[tid];
    if (tid == 128) part[128] = sq_l[0];
    if (tid == 129) part[129] = sq_l[1];
}

// ---------------- Kernel B: sequential head + parallel frozen tail ----------
__global__ __launch_bounds__(256) void kB(const float* __restrict__ ws,
                                          const float* __restrict__ p_lbs,
                                          const float* __restrict__ p_lon,
                                          const float* __restrict__ p_ltn,
                                          float* __restrict__ out) {
    __shared__ float s_lds[2][2048];
    __shared__ float Ycols[128];
    __shared__ float sh_sq[2];
    __shared__ float sh_stats[2][2];
    __shared__ float frz[16];          // A_c(0..8), K(9..11), S(12)
    __shared__ float mst[2][3];
    __shared__ float vx[2][128], vy[2][128], vz[2][128];
    __shared__ float Wm[7][9];
    __shared__ float wred[4];

    const int tid = threadIdx.x;

    // ---- copy s[g][t] from ws into LDS (4096 floats) ----
    {
        const float4* wsv = reinterpret_cast<const float4*>(ws);
        float4* sv = reinterpret_cast<float4*>(&s_lds[0][0]);
        for (int i = tid; i < 1024; i += 256) sv[i] = wsv[i];
    }
    // ---- reduce per-block partials ----
    if (tid < 128) {
        float a = 0.f;
        for (int b = 0; b < NBLK_A; ++b) a += ws[WS_PART + b*PART_STRIDE + tid];
        Ycols[tid] = a;
    }
    if (tid >= 128 && tid < 130) {
        float a = 0.f;
        for (int b = 0; b < NBLK_A; ++b) a += ws[WS_PART + b*PART_STRIDE + tid];
        sh_sq[tid - 128] = a;
    }
    __syncthreads();

    // ---- ssq = sum_t s[g][t]^2 (parallel) ----
    {
        const int g = tid >> 7, j = tid & 127;
        float a = 0.f;
        for (int t = j; t < TT; t += 128) { const float s = s_lds[g][t]; a += s*s; }
#pragma unroll
        for (int m = 1; m < 64; m <<= 1) a += __shfl_xor(a, m);
        if ((tid & 63) == 0) wred[tid >> 6] = a;
    }
    // ---- column-sum stats per group ----
    if (tid < 128) {
        const int w = tid >> 6, lane = tid & 63;
        const float y = Ycols[w*64 + lane];
        float su = y, s2 = y*y;
#pragma unroll
        for (int m = 1; m < 64; m <<= 1) {
            su += __shfl_xor(su, m);
            s2 += __shfl_xor(s2, m);
        }
        if (lane == 0) { sh_stats[w][0] = su; sh_stats[w][1] = s2; }
    }
    __syncthreads();

    float ssq0 = 0.f, ssq1 = 0.f;
    if (tid == 0) { ssq0 = wred[0] + wred[1]; ssq1 = wred[2] + wred[3]; }

    // ---- parameters ----
    const float sb2 = expf(2.0f * p_lbs[0]);
    const float so2 = expf(2.0f * p_lon[0]);
    const float tv  = expf(2.0f * p_ltn[0]);
    const float LOG2PI_F = 1.8378770664093453f;

    // ---- sequential exact filter, t = 0 .. T0-1 (lanes 0,1) ----
    float p = 0.f, vvel = 0.f, B = 0.f;
    float Ppp = 10000.f, Ppv = 0.f, PpB = 0.f, Pvv = 10000.f, PvB = 0.f, PBB = sb2;
    double llseq = 0.0;

    if (tid < 2) {
        const float tv3  = tv * (1.0f/3.0f);
        const float tv2h = tv * 0.5f;
        const float4* zr4 = reinterpret_cast<const float4*>(&s_lds[tid][0]);
        float4 zc = zr4[0];
        for (int bk = 0; bk < T0/4; ++bk) {
            const float4 zn = (bk < T0/4 - 1) ? zr4[bk+1] : zc;
#pragma unroll
            for (int u = 0; u < 4; ++u) {
                const float zraw = (u==0) ? zc.x : (u==1) ? zc.y : (u==2) ? zc.z : zc.w;
                // predict
                p += vvel;
                Ppp += 2.0f*Ppv + Pvv + tv3;
                Ppv += Pvv + tv2h;
                PpB += PvB;
                Pvv += tv;
                // update
                const float z   = zraw * 0.125f;
                const float Php = 8.0f*Ppp + PpB;
                const float Phv = 8.0f*Ppv + PvB;
                const float PhB = 8.0f*PpB + PBB;
                const float S   = 8.0f*Php + PhB + so2;
                const float r   = z - (8.0f*p + B);
                const float inv = 1.0f / S;
                llseq -= 0.5 * (double)(r*r*inv + __logf(S) + LOG2PI_F);
                const float kp = Php*inv, kv = Phv*inv, kB = PhB*inv;
                p    += kp*r; vvel += kv*r; B += kB*r;
                Ppp -= kp*Php; Ppv -= kp*Phv; PpB -= kp*PhB;
                Pvv -= kv*Phv; PvB -= kv*PhB; PBB -= kB*PhB;
            }
            zc = zn;
        }
        mst[tid][0] = p; mst[tid][1] = vvel; mst[tid][2] = B;
        if (tid == 0) {
            // one more predict on a copy -> frozen S, K, A_c
            const float Ap  = Ppp + 2.0f*Ppv + Pvv + tv*(1.0f/3.0f);
            const float Apv = Ppv + Pvv + tv*0.5f;
            const float ApB = PpB + PvB;
            const float Av  = Pvv + tv;
            const float AvB = PvB;
            const float AB  = PBB;
            const float Php = 8.0f*Ap  + ApB;
            const float Phv = 8.0f*Apv + AvB;
            const float PhB = 8.0f*ApB + AB;
            const float S   = 8.0f*Php + PhB + so2;
            const float K0 = Php/S, K1 = Phv/S, K2 = PhB/S;
            (void)Av;
            // A_c = (I - K h^T) F,  h^T F = (8, 8, 1), F = [[1,1,0],[0,1,0],[0,0,1]]
            frz[0] = 1.0f - 8.0f*K0; frz[1] = 1.0f - 8.0f*K0; frz[2] = -K0;
            frz[3] =      - 8.0f*K1; frz[4] = 1.0f - 8.0f*K1; frz[5] = -K1;
            frz[6] =      - 8.0f*K2; frz[7] =      - 8.0f*K2; frz[8] = 1.0f - K2;
            frz[9] = K0; frz[10] = K1; frz[11] = K2; frz[12] = S;
        }
    }
    // fold lane1's ll into lane0 (wave 0 fully active here)
    {
        const double ll1 = __shfl(llseq, 1);
        if (tid == 0) llseq += ll1;
    }
    __syncthreads();

    // ---- frozen-phase parallel scan: t = T0 .. TT-1 ----
    const float a00 = frz[0], a01 = frz[1], a02 = frz[2];
    const float a10 = frz[3], a11 = frz[4], a12 = frz[5];
    const float a20 = frz[6], a21 = frz[7], a22 = frz[8];
    const float k0r = frz[9], k1r = frz[10], k2r = frz[11];
    const float Sfz = frz[12];
    const int g = tid >> 7, j = tid & 127;
    const int tbase = T0 + j*CH;

    // chunk affine offset: c <- A_c c + K z   (13 steps)
    float cx = 0.f, cy = 0.f, cz = 0.f;
    for (int k = 0; k < CH; ++k) {
        const float z = s_lds[g][tbase + k] * 0.125f;
        const float nx = a00*cx + a01*cy + a02*cz + k0r*z;
        const float ny = a10*cx + a11*cy + a12*cz + k1r*z;
        const float nz = a20*cx + a21*cy + a22*cz + k2r*z;
        cx = nx; cy = ny; cz = nz;
    }

    // thread 0: build D = A_c^CH and its squarings for the scan
    if (tid == 0) {
        float A1[9];
#pragma unroll
        for (int k = 0; k < 9; ++k) A1[k] = frz[k];
        float A2[9], A4[9], A8[9], A12m[9], D[9];
        mmul3(A1, A1, A2);
        mmul3(A2, A2, A4);
        mmul3(A4, A4, A8);
        mmul3(A8, A4, A12m);
        mmul3(A12m, A1, D);        // A^13
#pragma unroll
        for (int k = 0; k < 9; ++k) Wm[0][k] = D[k];
        float Wc[9];
#pragma unroll
        for (int k = 0; k < 9; ++k) Wc[k] = D[k];
        for (int st = 1; st < 7; ++st) {
            float Wn[9];
            mmul3(Wc, Wc, Wn);
#pragma unroll
            for (int k = 0; k < 9; ++k) { Wm[st][k] = Wn[k]; Wc[k] = Wn[k]; }
        }
    }
    __syncthreads();

    // fold m_start into chunk 0
    if (j == 0) {
        const float mx0 = mst[g][0], my0 = mst[g][1], mz0 = mst[g][2];
        cx += Wm[0][0]*mx0 + Wm[0][1]*my0 + Wm[0][2]*mz0;
        cy += Wm[0][3]*mx0 + Wm[0][4]*my0 + Wm[0][5]*mz0;
        cz += Wm[0][6]*mx0 + Wm[0][7]*my0 + Wm[0][8]*mz0;
    }
    vx[g][j] = cx; vy[g][j] = cy; vz[g][j] = cz;
    __syncthreads();

    // Hillis-Steele scan over 128 chunks (per group)
    for (int st = 0; st < 7; ++st) {
        const int s = 1 << st;
        float px = 0.f, py = 0.f, pz = 0.f;
        if (j >= s) { px = vx[g][j-s]; py = vy[g][j-s]; pz = vz[g][j-s]; }
        __syncthreads();
        if (j >= s) {
            cx += Wm[st][0]*px + Wm[st][1]*py + Wm[st][2]*pz;
            cy += Wm[st][3]*px + Wm[st][4]*py + Wm[st][5]*pz;
            cz += Wm[st][6]*px + Wm[st][7]*py + Wm[st][8]*pz;
        }
        vx[g][j] = cx; vy[g][j] = cy; vz[g][j] = cz;
        __syncthreads();
    }

    // replay chunk: residuals with frozen gain
    float mx, my, mz;
    if (j == 0) { mx = mst[g][0]; my = mst[g][1]; mz = mst[g][2]; }
    else        { mx = vx[g][j-1]; my = vy[g][j-1]; mz = vz[g][j-1]; }
    float rs = 0.f;
    for (int k = 0; k < CH; ++k) {
        const float z  = s_lds[g][tbase + k] * 0.125f;
        const float pp = mx + my;                 // predict position
        const float r  = z - (8.0f*pp + mz);
        rs += r*r;
        mx = pp + k0r*r; my += k1r*r; mz += k2r*r;
    }
#pragma unroll
    for (int m = 1; m < 64; m <<= 1) rs += __shfl_xor(rs, m);
    if ((tid & 63) == 0) wred[tid >> 6] = rs;
    __syncthreads();

    // ---- final assembly ----
    if (tid == 0) {
        const double Sd = (double)Sfz;
        const double rsum = (double)(wred[0] + wred[1]) + (double)(wred[2] + wred[3]);
        const double LOG2PI = 1.8378770664093453;
        double llrem = -0.5*rsum/Sd - 0.5*2.0*(double)NREM*(log(Sd) + LOG2PI);

        // static bias modes (exact closed form)
        const float Q0 = sh_sq[0] - ssq0*(1.0f/64.0f);
        const float Q1 = sh_sq[1] - ssq1*(1.0f/64.0f);
        const float R0 = sh_stats[0][1] - sh_stats[0][0]*sh_stats[0][0]*(1.0f/64.0f);
        const float R1 = sh_stats[1][1] - sh_stats[1][0]*sh_stats[1][0]*(1.0f/64.0f);
        const double Td = (double)TT;
        const double denom = (double)so2 + Td*(double)sb2;
        double ll_static = -0.5*((double)Q0 + (double)Q1
                                 - (double)sb2*((double)R0 + (double)R1)/denom) / (double)so2;
        ll_static += -0.5*126.0*((Td - 1.0)*log((double)so2) + log(denom));
        ll_static += -0.5*126.0*Td*LOG2PI;

        out[0] = (float)(llseq + llrem + ll_static);
        // posterior mean: filter0 -> (x0, x2), filter1 -> (x1, x3)
        out[1] = vx[0][127]; out[2] = vx[1][127];
        out[3] = vy[0][127]; out[4] = vy[1][127];
        // posterior cov (both filters share the identical data-independent P)
        float C[16];
#pragma unroll
        for (int i = 0; i < 16; ++i) C[i] = 0.0f;
        C[0]  = Ppp; C[2]  = Ppv; C[8]  = Ppv; C[10] = Pvv;
        C[5]  = Ppp; C[7]  = Ppv; C[13] = Ppv; C[15] = Pvv;
#pragma unroll
        for (int i = 0; i < 16; ++i) out[5+i] = C[i];
    }
}

// ---------------- Fallback: round-1 single-kernel version ----------------
__global__ __launch_bounds__(256) void kf_fused(
    const float* __restrict__ obs,
    const float* __restrict__ p_lbs,
    const float* __restrict__ p_lon,
    const float* __restrict__ p_ltn,
    float* __restrict__ out) {
    __shared__ float s_lds[2][2048];
    __shared__ float Ycols[128];
    __shared__ float sh_sq[2];
    __shared__ float sh_ssq[2];
    __shared__ float sh_stats[2][2];
    const int tid = threadIdx.x;
    if (tid < 128) Ycols[tid] = 0.0f;
    if (tid < 2) { sh_sq[tid] = 0.0f; sh_ssq[tid] = 0.0f; }
    __syncthreads();
    const int q = tid & 31, rho = tid >> 5, g = q >> 4;
    float c0=0.f, c1=0.f, c2=0.f, c3=0.f, sq=0.f, ssq_acc=0.f;
    const float4* obs4 = reinterpret_cast<const float4*>(obs);
    for (int i = 0; i < TT/8; ++i) {
        const int row = i*8 + rho;
        const float4 v = obs4[row*32 + q];
        c0 += v.x; c1 += v.y; c2 += v.z; c3 += v.w;
        sq += v.x*v.x + v.y*v.y + v.z*v.z + v.w*v.w;
        float s = (v.x + v.y) + (v.z + v.w);
        s += __shfl_xor(s, 1); s += __shfl_xor(s, 2);
        s += __shfl_xor(s, 4); s += __shfl_xor(s, 8);
        if ((q & 15) == 0) { s_lds[g][row] = s; ssq_acc += s*s; }
    }
    atomicAdd(&sh_sq[g], sq);
    if ((q & 15) == 0) atomicAdd(&sh_ssq[g], ssq_acc);
    atomicAdd(&Ycols[4*q+0], c0); atomicAdd(&Ycols[4*q+1], c1);
    atomicAdd(&Ycols[4*q+2], c2); atomicAdd(&Ycols[4*q+3], c3);
    __syncthreads();
    if (tid < 128) {
        const int w = tid >> 6, lane = tid & 63;
        const float y = Ycols[w*64 + lane];
        float su = y, s2 = y*y;
#pragma unroll
        for (int m = 1; m < 64; m <<= 1) { su += __shfl_xor(su, m); s2 += __shfl_xor(s2, m); }
        if (lane == 0) { sh_stats[w][0] = su; sh_stats[w][1] = s2; }
    }
    __syncthreads();
    if (tid >= 64) return;
    const float sb2 = expf(2.0f * p_lbs[0]);
    const float so2 = expf(2.0f * p_lon[0]);
    const float tv  = expf(2.0f * p_ltn[0]);
    const float LOG2PI_F = 1.8378770664093453f;
    float p = 0.f, vv = 0.f, B = 0.f;
    float Ppp = 10000.f, Ppv = 0.f, PpB = 0.f, Pvv = 10000.f, PvB = 0.f, PBB = sb2;
    double ll = 0.0;
    if (tid < 2) {
        const float tv3 = tv*(1.0f/3.0f), tv2h = tv*0.5f;
        const float* zrow = s_lds[tid];
        for (int t = 0; t < TT; ++t) {
            p += vv;
            Ppp += 2.0f*Ppv + Pvv + tv3; Ppv += Pvv + tv2h; PpB += PvB; Pvv += tv;
            const float z = zrow[t]*0.125f;
            const float Php = 8.0f*Ppp + PpB, Phv = 8.0f*Ppv + PvB, PhB = 8.0f*PpB + PBB;
            const float S = 8.0f*Php + PhB + so2;
            const float r = z - (8.0f*p + B);
            const float inv = 1.0f/S;
            ll -= 0.5 * (double)(r*r*inv + __logf(S) + LOG2PI_F);
            const float kp = Php*inv, kv = Phv*inv, kB = PhB*inv;
            p += kp*r; vv += kv*r; B += kB*r;
            Ppp -= kp*Php; Ppv -= kp*Phv; PpB -= kp*PhB;
            Pvv -= kv*Phv; PvB -= kv*PhB; PBB -= kB*PhB;
        }
    }
    const float p1 = __shfl(p, 1), v1 = __shfl(vv, 1);
    const float Ppp1 = __shfl(Ppp, 1), Ppv1 = __shfl(Ppv, 1), Pvv1 = __shfl(Pvv, 1);
    const double ll1 = __shfl(ll, 1);
    if (tid == 0) {
        const float Q0 = sh_sq[0] - sh_ssq[0]*(1.0f/64.0f);
        const float Q1 = sh_sq[1] - sh_ssq[1]*(1.0f/64.0f);
        const float R0 = sh_stats[0][1] - sh_stats[0][0]*sh_stats[0][0]*(1.0f/64.0f);
        const float R1 = sh_stats[1][1] - sh_stats[1][0]*sh_stats[1][0]*(1.0f/64.0f);
        const double DLOG2PI = 1.8378770664093453;
        const double Td = (double)TT;
        const double denom = (double)so2 + Td*(double)sb2;
        double ll_static = -0.5*((double)Q0 + (double)Q1
                                 - (double)sb2*((double)R0 + (double)R1)/denom)/(double)so2;
        ll_static += -0.5*126.0*((Td - 1.0)*log((double)so2) + log(denom));
        ll_static += -0.5*126.0*Td*DLOG2PI;
        out[0] = (float)(ll + ll1 + ll_static);
        out[1] = p; out[2] = p1; out[3] = vv; out[4] = v1;
        float C[16];
#pragma unroll
        for (int i = 0; i < 16; ++i) C[i] = 0.0f;
        C[0] = Ppp; C[2] = Ppv; C[8] = Ppv; C[10] = Pvv;
        C[5] = Ppp1; C[7] = Ppv1; C[13] = Ppv1; C[15] = Pvv1;
#pragma unroll
        for (int i = 0; i < 16; ++i) out[5+i] = C[i];
    }
}

extern "C" void kernel_launch(void* const* d_in, const int* in_sizes, int n_in,
                              void* d_out, int out_size, void* d_ws, size_t ws_size,
                              hipStream_t stream) {
    const float* obs = (const float*)d_in[0];
    const float* lbs = (const float*)d_in[1];
    const float* lon = (const float*)d_in[2];
    const float* ltn = (const float*)d_in[3];
    float* out = (float*)d_out;
    if (ws_size >= WS_FLOATS * sizeof(float)) {
        float* ws = (float*)d_ws;
        hipLaunchKernelGGL(kA, dim3(NBLK_A), dim3(256), 0, stream, obs, ws);
        hipLaunchKernelGGL(kB, dim3(1), dim3(256), 0, stream, ws, lbs, lon, ltn, out);
    } else {
        hipLaunchKernelGGL(kf_fused, dim3(1), dim3(256), 0, stream,
                           obs, lbs, lon, ltn, out);
    }
}

// Round 3
// 24.351 us; speedup vs baseline: 14.0268x; 2.7680x over previous
//
#include <hip/hip_runtime.h>
#include <math.h>

#define TT 2000
#define T0 80                  // exact sequential steps (multiple of 8; T0/4 int)
#define NREM (TT - T0)         // 1920 = 64 * 30
#define CH 30                  // chunk length per scan thread (per group)
#define NCHUNK 64              // chunks per group (one wave)
#define NBLK_A 50
#define ROWS_PER_BLK 40        // 50*40 = 2000
#define WS_PART 4096           // float offset of per-block partials
#define PART_STRIDE 132        // 128 cols + 2 sq + pad
#define WS_FLOATS (WS_PART + NBLK_A * PART_STRIDE)

#if defined(__has_builtin)
#if __has_builtin(__builtin_amdgcn_rcpf)
#define FRCP(x) __builtin_amdgcn_rcpf(x)
#endif
#endif
#ifndef FRCP
#define FRCP(x) (1.0f / (x))
#endif

__device__ __forceinline__ void mmul3(const float* __restrict__ a,
                                      const float* __restrict__ b,
                                      float* __restrict__ c) {
#pragma unroll
    for (int r = 0; r < 3; ++r)
#pragma unroll
        for (int cc = 0; cc < 3; ++cc)
            c[3*r+cc] = a[3*r+0]*b[0+cc] + a[3*r+1]*b[3+cc] + a[3*r+2]*b[6+cc];
}

// ---------------- Kernel A: grid-parallel data reductions ----------------
__global__ __launch_bounds__(256) void kA(const float* __restrict__ obs,
                                          float* __restrict__ ws) {
    __shared__ float cols_l[128];
    __shared__ float sq_l[2];
    const int tid = threadIdx.x, b = blockIdx.x;
    if (tid < 128) cols_l[tid] = 0.0f;
    if (tid < 2)   sq_l[tid]   = 0.0f;
    __syncthreads();

    const int q = tid & 31, rho = tid >> 5, g = q >> 4;
    float c0=0.f, c1=0.f, c2=0.f, c3=0.f, sq=0.f;
    const float4* obs4 = reinterpret_cast<const float4*>(obs);
    for (int i = 0; i < ROWS_PER_BLK/8; ++i) {
        const int row = b*ROWS_PER_BLK + i*8 + rho;
        const float4 v = obs4[row*32 + q];
        c0 += v.x; c1 += v.y; c2 += v.z; c3 += v.w;
        sq += v.x*v.x + v.y*v.y + v.z*v.z + v.w*v.w;
        float s = (v.x + v.y) + (v.z + v.w);
        s += __shfl_xor(s, 1);
        s += __shfl_xor(s, 2);
        s += __shfl_xor(s, 4);
        s += __shfl_xor(s, 8);
        if ((q & 15) == 0) ws[g*2048 + row] = s;
    }
    atomicAdd(&cols_l[4*q+0], c0);
    atomicAdd(&cols_l[4*q+1], c1);
    atomicAdd(&cols_l[4*q+2], c2);
    atomicAdd(&cols_l[4*q+3], c3);
    atomicAdd(&sq_l[g], sq);
    __syncthreads();

    float* part = ws + WS_PART + b*PART_STRIDE;
    if (tid < 128) part[tid] = cols_l[tid];
    if (tid == 128) part[128] = sq_l[0];
    if (tid == 129) part[129] = sq_l[1];
}

// ---------------- Kernel B: short head + register-scan tail ----------------
__global__ __launch_bounds__(256) void kB(const float* __restrict__ ws,
                                          const float* __restrict__ p_lbs,
                                          const float* __restrict__ p_lon,
                                          const float* __restrict__ p_ltn,
                                          float* __restrict__ out) {
    __shared__ float s_lds[2][2048];
    __shared__ float colpart[2][128];
    __shared__ float sh_sqp[2][2];
    __shared__ float sh_ssq[2];
    __shared__ float sh_stats[2][2];
    __shared__ float frz[14];          // A_c(0..8), K(9..11), S(12)
    __shared__ float mst[2][3];
    __shared__ float Wm[6][9];         // A_c^(30*2^st)
    __shared__ float wred[2];
    __shared__ float vfin[2][3];
    __shared__ float sh_hll[4];        // r2[lane0], r2[lane1], logS[lane0], logS[lane1]

    const int tid  = threadIdx.x;
    const int lane = tid & 63;
    const int wave = tid >> 6;

    // ---- Phase 0 (all): copy s rows to LDS; reduce kA partials ----
    {
        const float4* wsv = reinterpret_cast<const float4*>(ws);
        float4* sv = reinterpret_cast<float4*>(&s_lds[0][0]);
#pragma unroll
        for (int i = 0; i < 4; ++i) sv[tid + 256*i] = wsv[tid + 256*i];
    }
    {
        const int c = tid & 127, half = tid >> 7;
        float a = 0.f;
        for (int b = half*25; b < half*25 + 25; ++b)
            a += ws[WS_PART + b*PART_STRIDE + c];
        colpart[half][c] = a;
    }
    if (tid < 4) {
        const int g = tid & 1, half = tid >> 1;
        float a = 0.f;
        for (int b = half*25; b < half*25 + 25; ++b)
            a += ws[WS_PART + b*PART_STRIDE + 128 + g];
        sh_sqp[g][half] = a;
    }
    __syncthreads();   // barrier 1

    // ---- parameters ----
    const float sb2 = expf(2.0f * p_lbs[0]);
    const float so2 = expf(2.0f * p_lon[0]);
    const float tv  = expf(2.0f * p_ltn[0]);
    const float LOG2PI_F = 1.8378770664093453f;

    // ---- Phase 1 (concurrent): head on lanes 0,1 of wave 0;
    //      ssq on waves 1,2; col stats on wave 3 ----
    float p = 0.f, vvel = 0.f, B = 0.f;
    float Ppp = 10000.f, Ppv = 0.f, PpB = 0.f, Pvv = 10000.f, PvB = 0.f, PBB = sb2;

    if (tid < 2) {
        const float tv3  = tv * (1.0f/3.0f);
        const float tv2h = tv * 0.5f;
        float acc_r2 = 0.f, acc_lS = 0.f;
        const float4* zr4 = reinterpret_cast<const float4*>(&s_lds[tid][0]);
        float4 zc = zr4[0];
        for (int bk = 0; bk < T0/4; ++bk) {
            const float4 zn = (bk < T0/4 - 1) ? zr4[bk+1] : zc;
#pragma unroll
            for (int u = 0; u < 4; ++u) {
                const float zraw = (u==0) ? zc.x : (u==1) ? zc.y : (u==2) ? zc.z : zc.w;
                p += vvel;
                Ppp += 2.0f*Ppv + Pvv + tv3;
                Ppv += Pvv + tv2h;
                PpB += PvB;
                Pvv += tv;
                const float z   = zraw * 0.125f;
                const float Php = 8.0f*Ppp + PpB;
                const float Phv = 8.0f*Ppv + PvB;
                const float PhB = 8.0f*PpB + PBB;
                const float S   = 8.0f*Php + PhB + so2;
                const float r   = z - (8.0f*p + B);
                const float inv = FRCP(S);
                acc_r2 += r*r*inv;
                acc_lS += __logf(S);
                const float kp = Php*inv, kv = Phv*inv, kB_ = PhB*inv;
                p    += kp*r; vvel += kv*r; B += kB_*r;
                Ppp -= kp*Php; Ppv -= kp*Phv; PpB -= kp*PhB;
                Pvv -= kv*Phv; PvB -= kv*PhB; PBB -= kB_*PhB;
            }
            zc = zn;
        }
        mst[tid][0] = p; mst[tid][1] = vvel; mst[tid][2] = B;
        sh_hll[tid]     = acc_r2;
        sh_hll[2 + tid] = acc_lS;
        if (tid == 0) {
            // one extra predict on copies -> frozen S, K, A_c
            const float Ap  = Ppp + 2.0f*Ppv + Pvv + tv*(1.0f/3.0f);
            const float Apv = Ppv + Pvv + tv*0.5f;
            const float ApB = PpB + PvB;
            const float AvB = PvB;
            const float AB  = PBB;
            const float Php = 8.0f*Ap  + ApB;
            const float Phv = 8.0f*Apv + AvB;
            const float PhB = 8.0f*ApB + AB;
            const float S   = 8.0f*Php + PhB + so2;
            const float inv = FRCP(S);
            const float K0 = Php*inv, K1 = Phv*inv, K2 = PhB*inv;
            frz[0] = 1.0f - 8.0f*K0; frz[1] = 1.0f - 8.0f*K0; frz[2] = -K0;
            frz[3] =      - 8.0f*K1; frz[4] = 1.0f - 8.0f*K1; frz[5] = -K1;
            frz[6] =      - 8.0f*K2; frz[7] =      - 8.0f*K2; frz[8] = 1.0f - K2;
            frz[9] = K0; frz[10] = K1; frz[11] = K2; frz[12] = S;
        }
    } else if (wave == 1 || wave == 2) {
        // ssq = sum_t s[g][t]^2
        const int g = wave - 1;
        float a = 0.f;
        for (int t = lane; t < TT; t += 64) { const float s = s_lds[g][t]; a += s*s; }
#pragma unroll
        for (int m = 1; m < 64; m <<= 1) a += __shfl_xor(a, m);
        if (lane == 0) sh_ssq[g] = a;
    } else if (wave == 3) {
        // column-sum stats per group
        const float y0 = colpart[0][lane]      + colpart[1][lane];
        const float y1 = colpart[0][64 + lane] + colpart[1][64 + lane];
        float su0 = y0, s20 = y0*y0, su1 = y1, s21 = y1*y1;
#pragma unroll
        for (int m = 1; m < 64; m <<= 1) {
            su0 += __shfl_xor(su0, m); s20 += __shfl_xor(s20, m);
            su1 += __shfl_xor(su1, m); s21 += __shfl_xor(s21, m);
        }
        if (lane == 0) {
            sh_stats[0][0] = su0; sh_stats[0][1] = s20;
            sh_stats[1][0] = su1; sh_stats[1][1] = s21;
        }
    }
    __syncthreads();   // barrier 2: frz ready

    // ---- Phase 2: chunk-local pass (waves 0,1) || Wm build (tid 128) ----
    const float a00 = frz[0], a01 = frz[1], a02 = frz[2];
    const float a10 = frz[3], a11 = frz[4], a12 = frz[5];
    const float a20 = frz[6], a21 = frz[7], a22 = frz[8];
    const float k0r = frz[9], k1r = frz[10], k2r = frz[11];
    const float Sfz = frz[12];

    float cx = 0.f, cy = 0.f, cz = 0.f;
    const int g2 = wave;              // scan: wave0 -> group0, wave1 -> group1
    const int tbase = T0 + lane*CH;
    if (tid < 128) {
        for (int k = 0; k < CH; ++k) {
            const float z = s_lds[g2][tbase + k] * 0.125f;
            const float nx = a00*cx + a01*cy + a02*cz + k0r*z;
            const float ny = a10*cx + a11*cy + a12*cz + k1r*z;
            const float nz = a20*cx + a21*cy + a22*cz + k2r*z;
            cx = nx; cy = ny; cz = nz;
        }
    } else if (tid == 128) {
        // A_c^30 and squarings: A2,A4,A8,A12,A14,A15, W0=A15^2, W1..W5
        float A1[9];
#pragma unroll
        for (int k = 0; k < 9; ++k) A1[k] = frz[k];
        float A2[9], A4[9], A8[9], A12m[9], A14[9], A15[9], W[9], Wn[9];
        mmul3(A1, A1, A2);
        mmul3(A2, A2, A4);
        mmul3(A4, A4, A8);
        mmul3(A8, A4, A12m);
        mmul3(A12m, A2, A14);
        mmul3(A14, A1, A15);
        mmul3(A15, A15, W);
#pragma unroll
        for (int k = 0; k < 9; ++k) Wm[0][k] = W[k];
        for (int st = 1; st < 6; ++st) {
            mmul3(W, W, Wn);
#pragma unroll
            for (int k = 0; k < 9; ++k) { Wm[st][k] = Wn[k]; W[k] = Wn[k]; }
        }
    }
    __syncthreads();   // barrier 3: Wm ready, chunk-local done

    if (tid < 128) {
        // fold m_start into chunk 0
        if (lane == 0) {
            const float mx0 = mst[g2][0], my0 = mst[g2][1], mz0 = mst[g2][2];
            cx += Wm[0][0]*mx0 + Wm[0][1]*my0 + Wm[0][2]*mz0;
            cy += Wm[0][3]*mx0 + Wm[0][4]*my0 + Wm[0][5]*mz0;
            cz += Wm[0][6]*mx0 + Wm[0][7]*my0 + Wm[0][8]*mz0;
        }
        // register Hillis-Steele scan, 6 stages, no barriers
#pragma unroll
        for (int st = 0; st < 6; ++st) {
            const int s = 1 << st;
            float px = __shfl_up(cx, s);
            float py = __shfl_up(cy, s);
            float pz = __shfl_up(cz, s);
            if (lane < s) { px = 0.f; py = 0.f; pz = 0.f; }
            cx += Wm[st][0]*px + Wm[st][1]*py + Wm[st][2]*pz;
            cy += Wm[st][3]*px + Wm[st][4]*py + Wm[st][5]*pz;
            cz += Wm[st][6]*px + Wm[st][7]*py + Wm[st][8]*pz;
        }
        if (lane == 63) { vfin[g2][0] = cx; vfin[g2][1] = cy; vfin[g2][2] = cz; }

        // exclusive prefix -> replay start
        float mx = __shfl_up(cx, 1);
        float my = __shfl_up(cy, 1);
        float mz = __shfl_up(cz, 1);
        if (lane == 0) { mx = mst[g2][0]; my = mst[g2][1]; mz = mst[g2][2]; }

        float rs = 0.f;
        for (int k = 0; k < CH; ++k) {
            const float z  = s_lds[g2][tbase + k] * 0.125f;
            const float pp = mx + my;
            const float r  = z - (8.0f*pp + mz);
            rs += r*r;
            mx = pp + k0r*r; my += k1r*r; mz += k2r*r;
        }
#pragma unroll
        for (int m = 1; m < 64; m <<= 1) rs += __shfl_xor(rs, m);
        if (lane == 0) wred[g2] = rs;
    }
    __syncthreads();   // barrier 4

    // ---- final assembly ----
    if (tid == 0) {
        const double LOG2PI = 1.8378770664093453;
        const double Sd = (double)Sfz;
        const double rsum = (double)wred[0] + (double)wred[1];
        const double llrem = -0.5*rsum/Sd - (double)NREM*(log(Sd) + LOG2PI);

        const double llseq = -0.5*((double)(sh_hll[0] + sh_hll[1])
                                 + (double)(sh_hll[2] + sh_hll[3]))
                             - (double)T0*LOG2PI;

        const float sq0 = sh_sqp[0][0] + sh_sqp[0][1];
        const float sq1 = sh_sqp[1][0] + sh_sqp[1][1];
        const float Q0 = sq0 - sh_ssq[0]*(1.0f/64.0f);
        const float Q1 = sq1 - sh_ssq[1]*(1.0f/64.0f);
        const float R0 = sh_stats[0][1] - sh_stats[0][0]*sh_stats[0][0]*(1.0f/64.0f);
        const float R1 = sh_stats[1][1] - sh_stats[1][0]*sh_stats[1][0]*(1.0f/64.0f);
        const double Td = (double)TT;
        const double denom = (double)so2 + Td*(double)sb2;
        double ll_static = -0.5*((double)Q0 + (double)Q1
                                 - (double)sb2*((double)R0 + (double)R1)/denom) / (double)so2;
        ll_static += -0.5*126.0*((Td - 1.0)*log((double)so2) + log(denom));
        ll_static += -0.5*126.0*Td*LOG2PI;

        out[0] = (float)(llseq + llrem + ll_static);
        out[1] = vfin[0][0]; out[2] = vfin[1][0];
        out[3] = vfin[0][1]; out[4] = vfin[1][1];
        float C[16];
#pragma unroll
        for (int i = 0; i < 16; ++i) C[i] = 0.0f;
        C[0]  = Ppp; C[2]  = Ppv; C[8]  = Ppv; C[10] = Pvv;
        C[5]  = Ppp; C[7]  = Ppv; C[13] = Ppv; C[15] = Pvv;
#pragma unroll
        for (int i = 0; i < 16; ++i) out[5+i] = C[i];
    }
}

// ---------------- Fallback: exact single-kernel version ----------------
__global__ __launch_bounds__(256) void kf_fused(
    const float* __restrict__ obs,
    const float* __restrict__ p_lbs,
    const float* __restrict__ p_lon,
    const float* __restrict__ p_ltn,
    float* __restrict__ out) {
    __shared__ float s_lds[2][2048];
    __shared__ float Ycols[128];
    __shared__ float sh_sq[2];
    __shared__ float sh_ssq[2];
    __shared__ float sh_stats[2][2];
    const int tid = threadIdx.x;
    if (tid < 128) Ycols[tid] = 0.0f;
    if (tid < 2) { sh_sq[tid] = 0.0f; sh_ssq[tid] = 0.0f; }
    __syncthreads();
    const int q = tid & 31, rho = tid >> 5, g = q >> 4;
    float c0=0.f, c1=0.f, c2=0.f, c3=0.f, sq=0.f, ssq_acc=0.f;
    const float4* obs4 = reinterpret_cast<const float4*>(obs);
    for (int i = 0; i < TT/8; ++i) {
        const int row = i*8 + rho;
        const float4 v = obs4[row*32 + q];
        c0 += v.x; c1 += v.y; c2 += v.z; c3 += v.w;
        sq += v.x*v.x + v.y*v.y + v.z*v.z + v.w*v.w;
        float s = (v.x + v.y) + (v.z + v.w);
        s += __shfl_xor(s, 1); s += __shfl_xor(s, 2);
        s += __shfl_xor(s, 4); s += __shfl_xor(s, 8);
        if ((q & 15) == 0) { s_lds[g][row] = s; ssq_acc += s*s; }
    }
    atomicAdd(&sh_sq[g], sq);
    if ((q & 15) == 0) atomicAdd(&sh_ssq[g], ssq_acc);
    atomicAdd(&Ycols[4*q+0], c0); atomicAdd(&Ycols[4*q+1], c1);
    atomicAdd(&Ycols[4*q+2], c2); atomicAdd(&Ycols[4*q+3], c3);
    __syncthreads();
    if (tid < 128) {
        const int w = tid >> 6, lane = tid & 63;
        const float y = Ycols[w*64 + lane];
        float su = y, s2 = y*y;
#pragma unroll
        for (int m = 1; m < 64; m <<= 1) { su += __shfl_xor(su, m); s2 += __shfl_xor(s2, m); }
        if (lane == 0) { sh_stats[w][0] = su; sh_stats[w][1] = s2; }
    }
    __syncthreads();
    if (tid >= 64) return;
    const float sb2 = expf(2.0f * p_lbs[0]);
    const float so2 = expf(2.0f * p_lon[0]);
    const float tv  = expf(2.0f * p_ltn[0]);
    const float LOG2PI_F = 1.8378770664093453f;
    float p = 0.f, vv = 0.f, B = 0.f;
    float Ppp = 10000.f, Ppv = 0.f, PpB = 0.f, Pvv = 10000.f, PvB = 0.f, PBB = sb2;
    double ll = 0.0;
    if (tid < 2) {
        const float tv3 = tv*(1.0f/3.0f), tv2h = tv*0.5f;
        const float* zrow = s_lds[tid];
        for (int t = 0; t < TT; ++t) {
            p += vv;
            Ppp += 2.0f*Ppv + Pvv + tv3; Ppv += Pvv + tv2h; PpB += PvB; Pvv += tv;
            const float z = zrow[t]*0.125f;
            const float Php = 8.0f*Ppp + PpB, Phv = 8.0f*Ppv + PvB, PhB = 8.0f*PpB + PBB;
            const float S = 8.0f*Php + PhB + so2;
            const float r = z - (8.0f*p + B);
            const float inv = 1.0f/S;
            ll -= 0.5 * (double)(r*r*inv + __logf(S) + LOG2PI_F);
            const float kp = Php*inv, kv = Phv*inv, kB = PhB*inv;
            p += kp*r; vv += kv*r; B += kB*r;
            Ppp -= kp*Php; Ppv -= kp*Phv; PpB -= kp*PhB;
            Pvv -= kv*Phv; PvB -= kv*PhB; PBB -= kB*PhB;
        }
    }
    const float p1 = __shfl(p, 1), v1 = __shfl(vv, 1);
    const float Ppp1 = __shfl(Ppp, 1), Ppv1 = __shfl(Ppv, 1), Pvv1 = __shfl(Pvv, 1);
    const double ll1 = __shfl(ll, 1);
    if (tid == 0) {
        const float Q0 = sh_sq[0] - sh_ssq[0]*(1.0f/64.0f);
        const float Q1 = sh_sq[1] - sh_ssq[1]*(1.0f/64.0f);
        const float R0 = sh_stats[0][1] - sh_stats[0][0]*sh_stats[0][0]*(1.0f/64.0f);
        const float R1 = sh_stats[1][1] - sh_stats[1][0]*sh_stats[1][0]*(1.0f/64.0f);
        const double DLOG2PI = 1.8378770664093453;
        const double Td = (double)TT;
        const double denom = (double)so2 + Td*(double)sb2;
        double ll_static = -0.5*((double)Q0 + (double)Q1
                                 - (double)sb2*((double)R0 + (double)R1)/denom)/(double)so2;
        ll_static += -0.5*126.0*((Td - 1.0)*log((double)so2) + log(denom));
        ll_static += -0.5*126.0*Td*DLOG2PI;
        out[0] = (float)(ll + ll1 + ll_static);
        out[1] = p; out[2] = p1; out[3] = vv; out[4] = v1;
        float C[16];
#pragma unroll
        for (int i = 0; i < 16; ++i) C[i] = 0.0f;
        C[0] = Ppp; C[2] = Ppv; C[8] = Ppv; C[10] = Pvv;
        C[5] = Ppp1; C[7] = Ppv1; C[13] = Ppv1; C[15] = Pvv1;
#pragma unroll
        for (int i = 0; i < 16; ++i) out[5+i] = C[i];
    }
}

extern "C" void kernel_launch(void* const* d_in, const int* in_sizes, int n_in,
                              void* d_out, int out_size, void* d_ws, size_t ws_size,
                              hipStream_t stream) {
    const float* obs = (const float*)d_in[0];
    const float* lbs = (const float*)d_in[1];
    const float* lon = (const float*)d_in[2];
    const float* ltn = (const float*)d_in[3];
    float* out = (float*)d_out;
    if (ws_size >= WS_FLOATS * sizeof(float)) {
        float* ws = (float*)d_ws;
        hipLaunchKernelGGL(kA, dim3(NBLK_A), dim3(256), 0, stream, obs, ws);
        hipLaunchKernelGGL(kB, dim3(1), dim3(256), 0, stream, ws, lbs, lon, ltn, out);
    } else {
        hipLaunchKernelGGL(kf_fused, dim3(1), dim3(256), 0, stream,
                           obs, lbs, lon, ltn, out);
    }
}

// Round 4
// 23.199 us; speedup vs baseline: 14.7235x; 1.0497x over previous
//
#include <hip/hip_runtime.h>
#include <math.h>

#define TT 2000
#define T0 80                  // exact sequential steps
#define NREM (TT - T0)         // 1920 = 64 * 30
#define CH 30                  // chunk length per scan thread (per group)
#define NPROD 50
#define RPB 40                 // rows per producer block (50*40 = 2000)
#define WS_PART 4096           // float offset of per-block partials
#define PART_STRIDE 132        // 128 cols + 2 sq + pad
#define WS_TOK 10696           // float offset of tokens (8B aligned: 10696*4 % 8 == 0)
#define WS_FLOATS 10800
#define MAGIC64 0x5DE1CAFEF00DB00FULL

#if defined(__has_builtin)
#if __has_builtin(__builtin_amdgcn_rcpf)
#define FRCP(x) __builtin_amdgcn_rcpf(x)
#endif
#endif
#ifndef FRCP
#define FRCP(x) (1.0f / (x))
#endif

__device__ __forceinline__ void mmul3(const float* __restrict__ a,
                                      const float* __restrict__ b,
                                      float* __restrict__ c) {
#pragma unroll
    for (int r = 0; r < 3; ++r)
#pragma unroll
        for (int cc = 0; cc < 3; ++cc)
            c[3*r+cc] = a[3*r+0]*b[0+cc] + a[3*r+1]*b[3+cc] + a[3*r+2]*b[6+cc];
}

// ---------------- Fused single-dispatch kernel ----------------
// blocks 1..50: producers (row group-sums -> ws, column/sq partials -> ws, token)
// block 0: consumer (own head rows, exact 80-step filter, poll, scan, assembly)
__global__ __launch_bounds__(256) void kf_one(const float* __restrict__ obs,
                                              float* __restrict__ ws,
                                              const float* __restrict__ p_lbs,
                                              const float* __restrict__ p_lon,
                                              const float* __restrict__ p_ltn,
                                              float* __restrict__ out) {
    __shared__ float s_lds[2][2048];
    __shared__ float colpart[128];
    __shared__ float sh_sq[2];
    __shared__ float sh_ssq[2];
    __shared__ float sh_stats[2][2];
    __shared__ float frz[14];          // A_c(0..8), K(9..11), S(12)
    __shared__ float mst[2][3];
    __shared__ float Wm[6][9];
    __shared__ float wred[2];
    __shared__ float vfin[2][3];
    __shared__ float sh_hll[4];

    const int tid  = threadIdx.x;
    const int lane = tid & 63;
    const int wave = tid >> 6;
    const float4* obs4 = reinterpret_cast<const float4*>(obs);
    unsigned long long* tok = reinterpret_cast<unsigned long long*>(ws + WS_TOK);

    if (blockIdx.x != 0) {
        // ---------------- producer ----------------
        const int bp = blockIdx.x - 1;
        if (tid < 128) colpart[tid] = 0.0f;
        if (tid < 2)   sh_sq[tid]   = 0.0f;
        __syncthreads();
        const int q = tid & 31, rho = tid >> 5, g = q >> 4;
        float c0=0.f, c1=0.f, c2=0.f, c3=0.f, sq=0.f;
        for (int i = 0; i < RPB/8; ++i) {
            const int row = bp*RPB + i*8 + rho;
            const float4 v = obs4[row*32 + q];
            c0 += v.x; c1 += v.y; c2 += v.z; c3 += v.w;
            sq += v.x*v.x + v.y*v.y + v.z*v.z + v.w*v.w;
            float s = (v.x + v.y) + (v.z + v.w);
            s += __shfl_xor(s, 1);
            s += __shfl_xor(s, 2);
            s += __shfl_xor(s, 4);
            s += __shfl_xor(s, 8);
            if ((q & 15) == 0) ws[g*2048 + row] = s;
        }
        atomicAdd(&colpart[4*q+0], c0);
        atomicAdd(&colpart[4*q+1], c1);
        atomicAdd(&colpart[4*q+2], c2);
        atomicAdd(&sh_sq[g], sq);
        atomicAdd(&colpart[4*q+3], c3);
        __syncthreads();
        float* part = ws + WS_PART + bp*PART_STRIDE;
        if (tid < 128) part[tid] = colpart[tid];
        if (tid == 128) part[128] = sh_sq[0];
        if (tid == 129) part[129] = sh_sq[1];
        __threadfence();           // make data agent-visible before token
        __syncthreads();
        if (tid == 0)
            __hip_atomic_store(&tok[bp], (unsigned long long)MAGIC64,
                               __ATOMIC_RELEASE, __HIP_MEMORY_SCOPE_AGENT);
        return;
    }

    // ---------------- consumer (block 0) ----------------
    // Step 1: compute own s rows 0..T0-1 directly from obs
    {
        const int q = tid & 31, rho = tid >> 5, g = q >> 4;
        for (int i = 0; i < T0/8; ++i) {
            const int row = i*8 + rho;
            const float4 v = obs4[row*32 + q];
            float s = (v.x + v.y) + (v.z + v.w);
            s += __shfl_xor(s, 1);
            s += __shfl_xor(s, 2);
            s += __shfl_xor(s, 4);
            s += __shfl_xor(s, 8);
            if ((q & 15) == 0) s_lds[g][row] = s;
        }
    }
    __syncthreads();   // b1: head rows ready

    const float sb2 = expf(2.0f * p_lbs[0]);
    const float so2 = expf(2.0f * p_lon[0]);
    const float tv  = expf(2.0f * p_ltn[0]);

    float Ppp = 10000.f, Ppv = 0.f, PpB = 0.f, Pvv = 10000.f, PvB = 0.f, PBB = sb2;

    if (wave == 0) {
        if (tid < 2) {
            // exact head filter, t = 0..T0-1
            const float tv3  = tv * (1.0f/3.0f);
            const float tv2h = tv * 0.5f;
            float p = 0.f, vvel = 0.f, B = 0.f;
            float acc_r2 = 0.f, acc_lS = 0.f;
            const float4* zr4 = reinterpret_cast<const float4*>(&s_lds[tid][0]);
            float4 zc = zr4[0];
            for (int bk = 0; bk < T0/4; ++bk) {
                const float4 zn = (bk < T0/4 - 1) ? zr4[bk+1] : zc;
#pragma unroll
                for (int u = 0; u < 4; ++u) {
                    const float zraw = (u==0) ? zc.x : (u==1) ? zc.y : (u==2) ? zc.z : zc.w;
                    p += vvel;
                    Ppp += 2.0f*Ppv + Pvv + tv3;
                    Ppv += Pvv + tv2h;
                    PpB += PvB;
                    Pvv += tv;
                    const float z   = zraw * 0.125f;
                    const float Php = 8.0f*Ppp + PpB;
                    const float Phv = 8.0f*Ppv + PvB;
                    const float PhB = 8.0f*PpB + PBB;
                    const float S   = 8.0f*Php + PhB + so2;
                    const float r   = z - (8.0f*p + B);
                    const float inv = FRCP(S);
                    acc_r2 += r*r*inv;
                    acc_lS += __logf(S);
                    const float kp = Php*inv, kv = Phv*inv, kB_ = PhB*inv;
                    p    += kp*r; vvel += kv*r; B += kB_*r;
                    Ppp -= kp*Php; Ppv -= kp*Phv; PpB -= kp*PhB;
                    Pvv -= kv*Phv; PvB -= kv*PhB; PBB -= kB_*PhB;
                }
                zc = zn;
            }
            mst[tid][0] = p; mst[tid][1] = vvel; mst[tid][2] = B;
            sh_hll[tid]     = acc_r2;
            sh_hll[2 + tid] = acc_lS;
            if (tid == 0) {
                // one extra predict on copies -> frozen S, K, A_c
                const float Ap  = Ppp + 2.0f*Ppv + Pvv + tv*(1.0f/3.0f);
                const float Apv = Ppv + Pvv + tv*0.5f;
                const float ApB = PpB + PvB;
                const float AvB = PvB;
                const float AB  = PBB;
                const float Php = 8.0f*Ap  + ApB;
                const float Phv = 8.0f*Apv + AvB;
                const float PhB = 8.0f*ApB + AB;
                const float S   = 8.0f*Php + PhB + so2;
                const float inv = FRCP(S);
                const float K0 = Php*inv, K1 = Phv*inv, K2 = PhB*inv;
                frz[0] = 1.0f - 8.0f*K0; frz[1] = 1.0f - 8.0f*K0; frz[2] = -K0;
                frz[3] =      - 8.0f*K1; frz[4] = 1.0f - 8.0f*K1; frz[5] = -K1;
                frz[6] =      - 8.0f*K2; frz[7] =      - 8.0f*K2; frz[8] = 1.0f - K2;
                frz[9] = K0; frz[10] = K1; frz[11] = K2; frz[12] = S;
            }
        }
    } else {
        // waves 1..3: poll tokens (relaxed), then acquire fence, then load tail
        bool ready = false;
        do {
            unsigned long long v = (lane < NPROD)
                ? __hip_atomic_load(&tok[lane], __ATOMIC_RELAXED, __HIP_MEMORY_SCOPE_AGENT)
                : (unsigned long long)MAGIC64;
            ready = (bool)__all(v == (unsigned long long)MAGIC64);
        } while (!ready);
        __builtin_amdgcn_fence(__ATOMIC_ACQUIRE, "agent");

        // tail s rows t in [T0, TT): 960 float4 across 192 threads
        const float4* wsv = reinterpret_cast<const float4*>(ws);
        float4* sv = reinterpret_cast<float4*>(&s_lds[0][0]);
        const int base = tid - 64;     // 0..191
#pragma unroll
        for (int i = 0; i < 5; ++i) {
            const int j = base + 192*i;              // 0..959
            const int g = (j >= 480) ? 1 : 0;
            const int k = j - g*480;                 // 0..479
            const int idx = g*512 + 20 + k;          // float4 index
            sv[idx] = wsv[idx];
        }
        // column partial reduction (threads with base < 128)
        if (base < 128) {
            float a = 0.f;
            for (int b = 0; b < NPROD; ++b) a += ws[WS_PART + b*PART_STRIDE + base];
            colpart[base] = a;
        }
        if (base < 2) {
            float a = 0.f;
            for (int b = 0; b < NPROD; ++b) a += ws[WS_PART + b*PART_STRIDE + 128 + base];
            sh_sq[base] = a;
        }
    }
    __syncthreads();   // b2: frz, tail s rows, colpart, sh_sq ready

    // ---- Phase C: chunk-local (waves 0,1) || Wm (tid 128) || stats (wave 3) ----
    const float a00 = frz[0], a01 = frz[1], a02 = frz[2];
    const float a10 = frz[3], a11 = frz[4], a12 = frz[5];
    const float a20 = frz[6], a21 = frz[7], a22 = frz[8];
    const float k0r = frz[9], k1r = frz[10], k2r = frz[11];
    const float Sfz = frz[12];
    const int g2 = wave;               // scan group for tid < 128
    const int tbase = T0 + lane*CH;

    float cx = 0.f, cy = 0.f, cz = 0.f;
    if (tid < 128) {
        for (int k = 0; k < CH; ++k) {
            const float z = s_lds[g2][tbase + k] * 0.125f;
            const float nx = a00*cx + a01*cy + a02*cz + k0r*z;
            const float ny = a10*cx + a11*cy + a12*cz + k1r*z;
            const float nz = a20*cx + a21*cy + a22*cz + k2r*z;
            cx = nx; cy = ny; cz = nz;
        }
    } else if (tid == 128) {
        // A_c^30, then squarings A_c^(30*2^st)
        float A1[9];
#pragma unroll
        for (int k = 0; k < 9; ++k) A1[k] = frz[k];
        float A2[9], A4[9], A8[9], A12m[9], A14[9], A15[9], W[9], Wn[9];
        mmul3(A1, A1, A2);
        mmul3(A2, A2, A4);
        mmul3(A4, A4, A8);
        mmul3(A8, A4, A12m);
        mmul3(A12m, A2, A14);
        mmul3(A14, A1, A15);
        mmul3(A15, A15, W);
#pragma unroll
        for (int k = 0; k < 9; ++k) Wm[0][k] = W[k];
        for (int st = 1; st < 6; ++st) {
            mmul3(W, W, Wn);
#pragma unroll
            for (int k = 0; k < 9; ++k) { Wm[st][k] = Wn[k]; W[k] = Wn[k]; }
        }
    } else if (wave == 3) {
        // column-sum stats per group
        const float y0 = colpart[lane];
        const float y1 = colpart[64 + lane];
        float su0 = y0, s20 = y0*y0, su1 = y1, s21 = y1*y1;
#pragma unroll
        for (int m = 1; m < 64; m <<= 1) {
            su0 += __shfl_xor(su0, m); s20 += __shfl_xor(s20, m);
            su1 += __shfl_xor(su1, m); s21 += __shfl_xor(s21, m);
        }
        if (lane == 0) {
            sh_stats[0][0] = su0; sh_stats[0][1] = s20;
            sh_stats[1][0] = su1; sh_stats[1][1] = s21;
        }
        // ssq = sum_t s[g][t]^2 over all t
        float A0 = 0.f, A1s = 0.f;
        for (int t = lane; t < TT; t += 64) {
            const float u0 = s_lds[0][t], u1 = s_lds[1][t];
            A0 += u0*u0; A1s += u1*u1;
        }
#pragma unroll
        for (int m = 1; m < 64; m <<= 1) {
            A0 += __shfl_xor(A0, m); A1s += __shfl_xor(A1s, m);
        }
        if (lane == 0) { sh_ssq[0] = A0; sh_ssq[1] = A1s; }
    }
    __syncthreads();   // b3: Wm ready, chunk-local done, stats done

    if (tid < 128) {
        // fold m_start into chunk 0
        if (lane == 0) {
            const float mx0 = mst[g2][0], my0 = mst[g2][1], mz0 = mst[g2][2];
            cx += Wm[0][0]*mx0 + Wm[0][1]*my0 + Wm[0][2]*mz0;
            cy += Wm[0][3]*mx0 + Wm[0][4]*my0 + Wm[0][5]*mz0;
            cz += Wm[0][6]*mx0 + Wm[0][7]*my0 + Wm[0][8]*mz0;
        }
        // register Hillis-Steele scan, 6 stages
#pragma unroll
        for (int st = 0; st < 6; ++st) {
            const int s = 1 << st;
            float px = __shfl_up(cx, s);
            float py = __shfl_up(cy, s);
            float pz = __shfl_up(cz, s);
            if (lane < s) { px = 0.f; py = 0.f; pz = 0.f; }
            cx += Wm[st][0]*px + Wm[st][1]*py + Wm[st][2]*pz;
            cy += Wm[st][3]*px + Wm[st][4]*py + Wm[st][5]*pz;
            cz += Wm[st][6]*px + Wm[st][7]*py + Wm[st][8]*pz;
        }
        if (lane == 63) { vfin[g2][0] = cx; vfin[g2][1] = cy; vfin[g2][2] = cz; }

        // exclusive prefix -> replay start
        float mx = __shfl_up(cx, 1);
        float my = __shfl_up(cy, 1);
        float mz = __shfl_up(cz, 1);
        if (lane == 0) { mx = mst[g2][0]; my = mst[g2][1]; mz = mst[g2][2]; }

        float rs = 0.f;
        for (int k = 0; k < CH; ++k) {
            const float z  = s_lds[g2][tbase + k] * 0.125f;
            const float pp = mx + my;
            const float r  = z - (8.0f*pp + mz);
            rs += r*r;
            mx = pp + k0r*r; my += k1r*r; mz += k2r*r;
        }
#pragma unroll
        for (int m = 1; m < 64; m <<= 1) rs += __shfl_xor(rs, m);
        if (lane == 0) wred[g2] = rs;
    }
    __syncthreads();   // b4

    // ---- final assembly ----
    if (tid == 0) {
        const double LOG2PI = 1.8378770664093453;
        const double Sd = (double)Sfz;
        const double rsum = (double)wred[0] + (double)wred[1];
        const double llrem = -0.5*rsum/Sd - (double)NREM*(log(Sd) + LOG2PI);

        const double llseq = -0.5*((double)(sh_hll[0] + sh_hll[1])
                                 + (double)(sh_hll[2] + sh_hll[3]))
                             - (double)T0*LOG2PI;

        const float Q0 = sh_sq[0] - sh_ssq[0]*(1.0f/64.0f);
        const float Q1 = sh_sq[1] - sh_ssq[1]*(1.0f/64.0f);
        const float R0 = sh_stats[0][1] - sh_stats[0][0]*sh_stats[0][0]*(1.0f/64.0f);
        const float R1 = sh_stats[1][1] - sh_stats[1][0]*sh_stats[1][0]*(1.0f/64.0f);
        const double Td = (double)TT;
        const double denom = (double)so2 + Td*(double)sb2;
        double ll_static = -0.5*((double)Q0 + (double)Q1
                                 - (double)sb2*((double)R0 + (double)R1)/denom) / (double)so2;
        ll_static += -0.5*126.0*((Td - 1.0)*log((double)so2) + log(denom));
        ll_static += -0.5*126.0*Td*LOG2PI;

        out[0] = (float)(llseq + llrem + ll_static);
        out[1] = vfin[0][0]; out[2] = vfin[1][0];
        out[3] = vfin[0][1]; out[4] = vfin[1][1];
        float C[16];
#pragma unroll
        for (int i = 0; i < 16; ++i) C[i] = 0.0f;
        C[0]  = Ppp; C[2]  = Ppv; C[8]  = Ppv; C[10] = Pvv;
        C[5]  = Ppp; C[7]  = Ppv; C[13] = Ppv; C[15] = Pvv;
#pragma unroll
        for (int i = 0; i < 16; ++i) out[5+i] = C[i];
    }
}

// ---------------- Fallback: exact single-kernel version ----------------
__global__ __launch_bounds__(256) void kf_fused(
    const float* __restrict__ obs,
    const float* __restrict__ p_lbs,
    const float* __restrict__ p_lon,
    const float* __restrict__ p_ltn,
    float* __restrict__ out) {
    __shared__ float s_lds[2][2048];
    __shared__ float Ycols[128];
    __shared__ float sh_sq[2];
    __shared__ float sh_ssq[2];
    __shared__ float sh_stats[2][2];
    const int tid = threadIdx.x;
    if (tid < 128) Ycols[tid] = 0.0f;
    if (tid < 2) { sh_sq[tid] = 0.0f; sh_ssq[tid] = 0.0f; }
    __syncthreads();
    const int q = tid & 31, rho = tid >> 5, g = q >> 4;
    float c0=0.f, c1=0.f, c2=0.f, c3=0.f, sq=0.f, ssq_acc=0.f;
    const float4* obs4 = reinterpret_cast<const float4*>(obs);
    for (int i = 0; i < TT/8; ++i) {
        const int row = i*8 + rho;
        const float4 v = obs4[row*32 + q];
        c0 += v.x; c1 += v.y; c2 += v.z; c3 += v.w;
        sq += v.x*v.x + v.y*v.y + v.z*v.z + v.w*v.w;
        float s = (v.x + v.y) + (v.z + v.w);
        s += __shfl_xor(s, 1); s += __shfl_xor(s, 2);
        s += __shfl_xor(s, 4); s += __shfl_xor(s, 8);
        if ((q & 15) == 0) { s_lds[g][row] = s; ssq_acc += s*s; }
    }
    atomicAdd(&sh_sq[g], sq);
    if ((q & 15) == 0) atomicAdd(&sh_ssq[g], ssq_acc);
    atomicAdd(&Ycols[4*q+0], c0); atomicAdd(&Ycols[4*q+1], c1);
    atomicAdd(&Ycols[4*q+2], c2); atomicAdd(&Ycols[4*q+3], c3);
    __syncthreads();
    if (tid < 128) {
        const int w = tid >> 6, lane = tid & 63;
        const float y = Ycols[w*64 + lane];
        float su = y, s2 = y*y;
#pragma unroll
        for (int m = 1; m < 64; m <<= 1) { su += __shfl_xor(su, m); s2 += __shfl_xor(s2, m); }
        if (lane == 0) { sh_stats[w][0] = su; sh_stats[w][1] = s2; }
    }
    __syncthreads();
    if (tid >= 64) return;
    const float sb2 = expf(2.0f * p_lbs[0]);
    const float so2 = expf(2.0f * p_lon[0]);
    const float tv  = expf(2.0f * p_ltn[0]);
    const float LOG2PI_F = 1.8378770664093453f;
    float p = 0.f, vv = 0.f, B = 0.f;
    float Ppp = 10000.f, Ppv = 0.f, PpB = 0.f, Pvv = 10000.f, PvB = 0.f, PBB = sb2;
    double ll = 0.0;
    if (tid < 2) {
        const float tv3 = tv*(1.0f/3.0f), tv2h = tv*0.5f;
        const float* zrow = s_lds[tid];
        for (int t = 0; t < TT; ++t) {
            p += vv;
            Ppp += 2.0f*Ppv + Pvv + tv3; Ppv += Pvv + tv2h; PpB += PvB; Pvv += tv;
            const float z = zrow[t]*0.125f;
            const float Php = 8.0f*Ppp + PpB, Phv = 8.0f*Ppv + PvB, PhB = 8.0f*PpB + PBB;
            const float S = 8.0f*Php + PhB + so2;
            const float r = z - (8.0f*p + B);
            const float inv = 1.0f/S;
            ll -= 0.5 * (double)(r*r*inv + __logf(S) + LOG2PI_F);
            const float kp = Php*inv, kv = Phv*inv, kB = PhB*inv;
            p += kp*r; vv += kv*r; B += kB*r;
            Ppp -= kp*Php; Ppv -= kp*Phv; PpB -= kp*PhB;
            Pvv -= kv*Phv; PvB -= kv*PhB; PBB -= kB*PhB;
        }
    }
    const float p1 = __shfl(p, 1), v1 = __shfl(vv, 1);
    const float Ppp1 = __shfl(Ppp, 1), Ppv1 = __shfl(Ppv, 1), Pvv1 = __shfl(Pvv, 1);
    const double ll1 = __shfl(ll, 1);
    if (tid == 0) {
        const float Q0 = sh_sq[0] - sh_ssq[0]*(1.0f/64.0f);
        const float Q1 = sh_sq[1] - sh_ssq[1]*(1.0f/64.0f);
        const float R0 = sh_stats[0][1] - sh_stats[0][0]*sh_stats[0][0]*(1.0f/64.0f);
        const float R1 = sh_stats[1][1] - sh_stats[1][0]*sh_stats[1][0]*(1.0f/64.0f);
        const double DLOG2PI = 1.8378770664093453;
        const double Td = (double)TT;
        const double denom = (double)so2 + Td*(double)sb2;
        double ll_static = -0.5*((double)Q0 + (double)Q1
                                 - (double)sb2*((double)R0 + (double)R1)/denom)/(double)so2;
        ll_static += -0.5*126.0*((Td - 1.0)*log((double)so2) + log(denom));
        ll_static += -0.5*126.0*Td*DLOG2PI;
        out[0] = (float)(ll + ll1 + ll_static);
        out[1] = p; out[2] = p1; out[3] = vv; out[4] = v1;
        float C[16];
#pragma unroll
        for (int i = 0; i < 16; ++i) C[i] = 0.0f;
        C[0] = Ppp; C[2] = Ppv; C[8] = Ppv; C[10] = Pvv;
        C[5] = Ppp1; C[7] = Ppv1; C[13] = Ppv1; C[15] = Pvv1;
#pragma unroll
        for (int i = 0; i < 16; ++i) out[5+i] = C[i];
    }
}

extern "C" void kernel_launch(void* const* d_in, const int* in_sizes, int n_in,
                              void* d_out, int out_size, void* d_ws, size_t ws_size,
                              hipStream_t stream) {
    const float* obs = (const float*)d_in[0];
    const float* lbs = (const float*)d_in[1];
    const float* lon = (const float*)d_in[2];
    const float* ltn = (const float*)d_in[3];
    float* out = (float*)d_out;
    if (ws_size >= WS_FLOATS * sizeof(float)) {
        float* ws = (float*)d_ws;
        hipLaunchKernelGGL(kf_one, dim3(NPROD + 1), dim3(256), 0, stream,
                           obs, ws, lbs, lon, ltn, out);
    } else {
        hipLaunchKernelGGL(kf_fused, dim3(1), dim3(256), 0, stream,
                           obs, lbs, lon, ltn, out);
    }
}